// Round 6
// baseline (133.264 us; speedup 1.0000x reference)
//
#include <hip/hip_runtime.h>

#define BB 8
#define NN 256
#define DD 128
#define HH 512
#define LL 2
#define EPSV 1e-5f
#define TPB 4            // tokens per block
#define BPB (NN/TPB)     // pool partials per batch = 64

__device__ __forceinline__ void waveRed2(float &a, float &b){
  #pragma unroll
  for (int off=32; off>=1; off>>=1){
    a += __shfl_xor(a, off, 64);
    b += __shfl_xor(b, off, 64);
  }
}

__device__ __forceinline__ void poolMerge(float &m1, float &m2, int &am,
                                          float o1, float o2, int oa){
  if (o1 > m1){ m2 = fmaxf(m1, o2); m1 = o1; am = oa; }
  else        { m2 = fmaxf(m2, o1); }
}

// ---- embed + LN + pool-partial: 512 thr = (token 0..3) x (d 0..127) ----
__global__ __launch_bounds__(512) void k_embed(
    const float* __restrict__ x, const float* __restrict__ We,
    const float* __restrict__ be, const float* __restrict__ ge,
    const float* __restrict__ bge, float* __restrict__ h,
    float* __restrict__ pm1p, float* __restrict__ pm2p, int* __restrict__ pargp)
{
  int tid = threadIdx.x;
  int t = tid >> 7, d = tid & 127;
  int lane = tid & 63, wid = (tid >> 6) & 1;
  int t0 = blockIdx.x * TPB;
  int tok = t0 + t;
  __shared__ float red[TPB][2][2];
  __shared__ float hf[TPB][DD];
  float x0 = x[tok*2], x1 = x[tok*2+1];
  float v = fmaf(x0, We[d], fmaf(x1, We[DD+d], be[d]));
  float s=v, q=v*v; waveRed2(s,q);
  if (lane==0){ red[t][wid][0]=s; red[t][wid][1]=q; }
  __syncthreads();
  float S=red[t][0][0]+red[t][1][0], Q=red[t][0][1]+red[t][1][1];
  float m=S*(1.f/DD), var=Q*(1.f/DD)-m*m, rs=rsqrtf(var+EPSV);
  float hv = (v-m)*rs*ge[d] + bge[d];
  h[(size_t)tok*DD + d] = hv;
  hf[t][d] = hv;
  __syncthreads();
  if (t==0){
    int b = t0 >> 8;
    int n0 = t0 & 255;
    float m1 = hf[0][d], m2 = -3.4e38f; int am = n0;
    #pragma unroll
    for (int p=1;p<TPB;++p) poolMerge(m1,m2,am, hf[p][d], -3.4e38f, n0+p);
    int blk = (t0 >> 2) & (BPB-1);
    size_t idx = ((size_t)b*BPB + blk)*DD + d;
    pm1p[idx]=m1; pm2p[idx]=m2; pargp[idx]=am;
  }
}

// ---- fused layer, float4 weight quads + split-K.
// 512 threads; all weight loads are dwordx4 (thread owns 4 output columns).
// Stage A/C: (q 0..31 col-quad) x (p 0..15 k-part); stage B: (J 0..127) x (p 0..3).
// Partials meet in a 32 KB LDS buffer. h updated in place (h == d_out).
__global__ __launch_bounds__(512) void k_layer(
    float* __restrict__ h,
    const float* __restrict__ pm1p, const float* __restrict__ pm2p,
    const int* __restrict__ pargp,
    float* __restrict__ qm1p, float* __restrict__ qm2p, int* __restrict__ qargp,
    int write_pool,
    const float* __restrict__ Wp, const float* __restrict__ bp,
    const float* __restrict__ gp, const float* __restrict__ bgp,
    const float* __restrict__ W1, const float* __restrict__ b1,
    const float* __restrict__ W2, const float* __restrict__ b2,
    const float* __restrict__ gf, const float* __restrict__ bgf)
{
  int tid = threadIdx.x;
  int d = tid & 127;            // for combine phases / pool merge
  int fourth = tid >> 7;        // 0..3
  int lane = tid & 63, wid = (tid >> 6) & 1;
  int t0 = blockIdx.x * TPB;
  int b = t0 >> 8;

  __shared__ float cat[TPB][2*DD];       // 4 KB (reused as final-h buffer)
  __shared__ float h1s[TPB][DD];         // 2 KB
  __shared__ float us[TPB][HH];          // 8 KB
  __shared__ float pf[16*TPB*DD];        // 32 KB partials (A, B, C reuse)
  __shared__ float red[TPB][2][2];
  __shared__ float fm1[DD], fm2[DD];
  __shared__ int   fam[DD];
  __shared__ float sm1[4][DD], sm2[4][DD];
  __shared__ int   sam[4][DD];

  // ---- merge the batch's 64 pool partials (16 per fourth) ----
  {
    size_t base = ((size_t)b*BPB + fourth*16)*DD + d;
    float m1 = pm1p[base], m2 = pm2p[base]; int am = pargp[base];
    #pragma unroll
    for (int i=1;i<16;++i)
      poolMerge(m1,m2,am, pm1p[base+(size_t)i*DD], pm2p[base+(size_t)i*DD],
                pargp[base+(size_t)i*DD]);
    sm1[fourth][d]=m1; sm2[fourth][d]=m2; sam[fourth][d]=am;
  }
  __syncthreads();
  if (fourth==0){
    float m1=sm1[0][d], m2=sm2[0][d]; int am=sam[0][d];
    #pragma unroll
    for (int p=1;p<4;++p) poolMerge(m1,m2,am, sm1[p][d], sm2[p][d], sam[p][d]);
    fm1[d]=m1; fm2[d]=m2; fam[d]=am;
  }
  __syncthreads();

  // ---- build cat[4][256]: 2 entries per thread, wave-uniform branch ----
  #pragma unroll
  for (int rep=0; rep<2; ++rep){
    int e = rep*512 + tid;
    int t = e >> 8, c = e & 255;
    int tok = t0 + t, n = (t0 & 255) + t;
    float v;
    if (c < DD) v = h[(size_t)tok*DD + c];
    else { int cc = c - DD; v = (n==fam[cc]) ? fm2[cc] : fm1[cc]; }
    cat[t][c] = v;
  }
  __syncthreads();

  // ---- stage A: y[4q..4q+3] partial over k in [16p,16p+16) ----
  {
    int q = tid & 31, p = tid >> 5;
    float4 acc[TPB];
    #pragma unroll
    for (int t=0;t<TPB;++t) acc[t] = make_float4(0.f,0.f,0.f,0.f);
    const float* wp = Wp + 4*q;
    int k0 = p*16;
    #pragma unroll
    for (int kk=0; kk<16; ++kk){
      int k = k0 + kk;
      float4 w = *(const float4*)&wp[k*DD];
      #pragma unroll
      for (int t=0;t<TPB;++t){
        float c = cat[t][k];
        acc[t].x = fmaf(c, w.x, acc[t].x);
        acc[t].y = fmaf(c, w.y, acc[t].y);
        acc[t].z = fmaf(c, w.z, acc[t].z);
        acc[t].w = fmaf(c, w.w, acc[t].w);
      }
    }
    #pragma unroll
    for (int t=0;t<TPB;++t)
      *(float4*)&pf[((p*TPB)+t)*DD + 4*q] = acc[t];
  }
  __syncthreads();

  // ---- combine A: sum 16 partials + bias + residual, LN -> h1s ----
  {
    int t = fourth;
    float v = 0.f;
    #pragma unroll
    for (int p=0;p<16;++p) v += pf[((p*TPB)+t)*DD + d];
    v += bp[d] + cat[t][d];
    float s=v,q=v*v; waveRed2(s,q);
    if (lane==0){ red[t][wid][0]=s; red[t][wid][1]=q; }
    __syncthreads();
    float S=red[t][0][0]+red[t][1][0], Q=red[t][0][1]+red[t][1][1];
    float m=S*(1.f/DD), var=Q*(1.f/DD)-m*m, rs=rsqrtf(var+EPSV);
    h1s[t][d] = (v-m)*rs*gp[d] + bgp[d];
  }
  __syncthreads();

  // ---- stage B: u[4J..4J+3] partial over k in [32p,32p+32) ----
  {
    int J = tid & 127, p = tid >> 7;
    float4 acc[TPB];
    #pragma unroll
    for (int t=0;t<TPB;++t) acc[t] = make_float4(0.f,0.f,0.f,0.f);
    const float* w1p = W1 + 4*J;
    int k0 = p*32;
    #pragma unroll
    for (int kk=0; kk<32; ++kk){
      int k = k0 + kk;
      float4 w = *(const float4*)&w1p[k*HH];
      #pragma unroll
      for (int t=0;t<TPB;++t){
        float c = h1s[t][k];
        acc[t].x = fmaf(c, w.x, acc[t].x);
        acc[t].y = fmaf(c, w.y, acc[t].y);
        acc[t].z = fmaf(c, w.z, acc[t].z);
        acc[t].w = fmaf(c, w.w, acc[t].w);
      }
    }
    #pragma unroll
    for (int t=0;t<TPB;++t)
      *(float4*)&pf[((p*TPB)+t)*HH + 4*J] = acc[t];
  }
  __syncthreads();

  // ---- combine B: sum 4 partials + bias, relu -> us (4 j's per thread) ----
  {
    int j = tid;
    float b1v = b1[j];
    #pragma unroll
    for (int t=0;t<TPB;++t){
      float v = pf[((0*TPB)+t)*HH + j] + pf[((1*TPB)+t)*HH + j]
              + pf[((2*TPB)+t)*HH + j] + pf[((3*TPB)+t)*HH + j];
      us[t][j] = fmaxf(v + b1v, 0.f);
    }
  }
  __syncthreads();

  // ---- stage C: z[4q..4q+3] partial over j in [32p,32p+32) ----
  {
    int q = tid & 31, p = tid >> 5;
    float4 acc[TPB];
    #pragma unroll
    for (int t=0;t<TPB;++t) acc[t] = make_float4(0.f,0.f,0.f,0.f);
    const float* w2p = W2 + 4*q;
    int j0 = p*32;
    #pragma unroll
    for (int jj=0; jj<32; ++jj){
      int j = j0 + jj;
      float4 w = *(const float4*)&w2p[j*DD];
      #pragma unroll
      for (int t=0;t<TPB;++t){
        float c = us[t][j];
        acc[t].x = fmaf(c, w.x, acc[t].x);
        acc[t].y = fmaf(c, w.y, acc[t].y);
        acc[t].z = fmaf(c, w.z, acc[t].z);
        acc[t].w = fmaf(c, w.w, acc[t].w);
      }
    }
    __syncthreads();    // us/pf(B) reads done before overwriting pf
    #pragma unroll
    for (int t=0;t<TPB;++t)
      *(float4*)&pf[((p*TPB)+t)*DD + 4*q] = acc[t];
  }
  __syncthreads();

  // ---- combine C: sum 16 partials + bias + residual, LN -> h + pool ----
  {
    int t = fourth;
    float v = 0.f;
    #pragma unroll
    for (int p=0;p<16;++p) v += pf[((p*TPB)+t)*DD + d];
    v += b2[d] + h1s[t][d];
    float s=v,q=v*v; waveRed2(s,q);
    if (lane==0){ red[t][wid][0]=s; red[t][wid][1]=q; }
    __syncthreads();
    float S=red[t][0][0]+red[t][1][0], Q=red[t][0][1]+red[t][1][1];
    float m=S*(1.f/DD), var=Q*(1.f/DD)-m*m, rs=rsqrtf(var+EPSV);
    float hv = (v-m)*rs*gf[d] + bgf[d];
    h[(size_t)(t0+t)*DD + d] = hv;
    cat[t][d] = hv;
  }
  if (write_pool){
    __syncthreads();
    if (fourth==0){
      int n0 = t0 & 255;
      float m1 = cat[0][d], m2=-3.4e38f; int am=n0;
      #pragma unroll
      for (int p=1;p<TPB;++p) poolMerge(m1,m2,am, cat[p][d], -3.4e38f, n0+p);
      int blk = (t0>>2)&(BPB-1);
      size_t idx = ((size_t)b*BPB+blk)*DD + d;
      qm1p[idx]=m1; qm2p[idx]=m2; qargp[idx]=am;
    }
  }
}

extern "C" void kernel_launch(void* const* d_in, const int* in_sizes, int n_in,
                              void* d_out, int out_size, void* d_ws, size_t ws_size,
                              hipStream_t stream)
{
  const float* x   = (const float*)d_in[0];
  const float* We  = (const float*)d_in[1];
  const float* be  = (const float*)d_in[2];
  const float* ge  = (const float*)d_in[3];
  const float* bge = (const float*)d_in[4];
  const float* Wp  = (const float*)d_in[5];
  const float* bp  = (const float*)d_in[6];
  const float* gp  = (const float*)d_in[7];
  const float* bgp = (const float*)d_in[8];
  const float* W1  = (const float*)d_in[9];
  const float* b1  = (const float*)d_in[10];
  const float* W2  = (const float*)d_in[11];
  const float* b2  = (const float*)d_in[12];
  const float* gf  = (const float*)d_in[13];
  const float* bgf = (const float*)d_in[14];

  // h lives in d_out; final layer's in-place update IS the output.
  float* h = (float*)d_out;
  const size_t NSTAT = (size_t)BB*BPB*DD;
  float* pA1 = (float*)d_ws;
  float* pA2 = pA1 + NSTAT;
  int*   pAa = (int*)(pA2 + NSTAT);
  float* pB1 = (float*)(pAa + NSTAT);
  float* pB2 = pB1 + NSTAT;
  int*   pBa = (int*)(pB2 + NSTAT);

  const int grid = (BB*NN)/TPB;   // 512

  k_embed<<<grid, 512, 0, stream>>>(x, We, be, ge, bge, h, pA1, pA2, pAa);

  k_layer<<<grid, 512, 0, stream>>>(h, pA1, pA2, pAa, pB1, pB2, pBa, 1,
      Wp,                bp,        gp,        bgp,
      W1,                b1,        W2,        b2,
      gf,                bgf);

  k_layer<<<grid, 512, 0, stream>>>(h, pB1, pB2, pBa, pB1, pB2, pBa, 0,
      Wp + (size_t)2*DD*DD, bp + DD,  gp + DD,  bgp + DD,
      W1 + (size_t)DD*HH,   b1 + HH,  W2 + (size_t)HH*DD, b2 + DD,
      gf + DD,              bgf + DD);
}

// Round 7
// 125.033 us; speedup vs baseline: 1.0658x; 1.0658x over previous
//
#include <hip/hip_runtime.h>
#include <hip/hip_bf16.h>

#define BB 8
#define NN 256
#define DD 128
#define HH 512
#define LL 2
#define EPSV 1e-5f
#define TPE 4            // tokens per block in k_embed
#define TPB 8            // tokens per block in k_layer
#define BPE (NN/TPE)     // embed pool partials per batch = 64
#define BPL (NN/TPB)     // layer pool partials per batch = 32

typedef unsigned short ushort_t;
typedef unsigned int uint_t;

__device__ __forceinline__ void waveRed2(float &a, float &b){
  #pragma unroll
  for (int off=32; off>=1; off>>=1){
    a += __shfl_xor(a, off, 64);
    b += __shfl_xor(b, off, 64);
  }
}

__device__ __forceinline__ void poolMerge(float &m1, float &m2, int &am,
                                          float o1, float o2, int oa){
  if (o1 > m1){ m2 = fmaxf(m1, o2); m1 = o1; am = oa; }
  else        { m2 = fmaxf(m2, o1); }
}

__device__ __forceinline__ void unp4(uint2 wb, float &a, float &b,
                                     float &c, float &d){
  a = __uint_as_float(wb.x << 16);
  b = __uint_as_float(wb.x & 0xffff0000u);
  c = __uint_as_float(wb.y << 16);
  d = __uint_as_float(wb.y & 0xffff0000u);
}

// ---- weight f32 -> bf16 pack (runs every launch; graph-safe) ----
__global__ __launch_bounds__(512) void k_conv(
    const float* __restrict__ Wp, const float* __restrict__ W1,
    const float* __restrict__ W2, ushort_t* __restrict__ wpb,
    ushort_t* __restrict__ w1b, ushort_t* __restrict__ w2b)
{
  int i = blockIdx.x*512 + threadIdx.x;       // 0 .. 327679
  const int NP = LL*2*DD*DD;                  // 65536
  const int N1 = LL*DD*HH;                    // 131072
  float v; ushort_t* dst; int o;
  if (i < NP){ v = Wp[i]; dst = wpb; o = i; }
  else if (i < NP+N1){ o = i-NP; v = W1[o]; dst = w1b; }
  else { o = i-NP-N1; v = W2[o]; dst = w2b; }
  __hip_bfloat16 hv = __float2bfloat16(v);
  dst[o] = *(ushort_t*)&hv;
}

// ---- embed + LN + pool-partial: 512 thr = (token 0..3) x (d 0..127) ----
__global__ __launch_bounds__(512) void k_embed(
    const float* __restrict__ x, const float* __restrict__ We,
    const float* __restrict__ be, const float* __restrict__ ge,
    const float* __restrict__ bge, float* __restrict__ h,
    float* __restrict__ pm1p, float* __restrict__ pm2p, int* __restrict__ pargp)
{
  int tid = threadIdx.x;
  int t = tid >> 7, d = tid & 127;
  int lane = tid & 63, wid = (tid >> 6) & 1;
  int t0 = blockIdx.x * TPE;
  int tok = t0 + t;
  __shared__ float red[TPE][2][2];
  __shared__ float hf[TPE][DD];
  float x0 = x[tok*2], x1 = x[tok*2+1];
  float v = fmaf(x0, We[d], fmaf(x1, We[DD+d], be[d]));
  float s=v, q=v*v; waveRed2(s,q);
  if (lane==0){ red[t][wid][0]=s; red[t][wid][1]=q; }
  __syncthreads();
  float S=red[t][0][0]+red[t][1][0], Q=red[t][0][1]+red[t][1][1];
  float m=S*(1.f/DD), var=Q*(1.f/DD)-m*m, rs=rsqrtf(var+EPSV);
  float hv = (v-m)*rs*ge[d] + bge[d];
  h[(size_t)tok*DD + d] = hv;
  hf[t][d] = hv;
  __syncthreads();
  if (t==0){
    int b = t0 >> 8;
    int n0 = t0 & 255;
    float m1 = hf[0][d], m2 = -3.4e38f; int am = n0;
    #pragma unroll
    for (int p=1;p<TPE;++p) poolMerge(m1,m2,am, hf[p][d], -3.4e38f, n0+p);
    int blk = (t0 >> 2) & (BPE-1);
    size_t idx = ((size_t)b*BPE + blk)*DD + d;
    pm1p[idx]=m1; pm2p[idx]=m2; pargp[idx]=am;
  }
}

// ---- fused layer, bf16 weights, TPB=8 tokens/block, grid 256.
// Stage A: (q 0..31 col-quad) x (p 0..15, k-chunk 16); 64 KB pf partials.
// Stage B: (J 0..127 col-quad) x (p 0..3, k-chunk 32).
// Stage C: (q 0..31) x (p 0..15, j-chunk 32). h in place (h == d_out).
__global__ __launch_bounds__(512) void k_layer(
    float* __restrict__ h,
    const float* __restrict__ pm1p, const float* __restrict__ pm2p,
    const int* __restrict__ pargp, int npart,
    float* __restrict__ qm1p, float* __restrict__ qm2p, int* __restrict__ qargp,
    int write_pool,
    const ushort_t* __restrict__ Wp, const float* __restrict__ bp,
    const float* __restrict__ gp, const float* __restrict__ bgp,
    const ushort_t* __restrict__ W1, const float* __restrict__ b1,
    const ushort_t* __restrict__ W2, const float* __restrict__ b2,
    const float* __restrict__ gf, const float* __restrict__ bgf)
{
  int tid = threadIdx.x;
  int d = tid & 127;
  int fourth = tid >> 7;        // 0..3
  int lane = tid & 63, wid = (tid >> 6) & 1;
  int t0 = blockIdx.x * TPB;
  int b = t0 >> 8;

  __shared__ float cat[TPB][2*DD];       // 8 KB (reused as final-h buffer)
  __shared__ float h1s[TPB][DD];         // 4 KB
  __shared__ float us[TPB][HH];          // 16 KB
  __shared__ float pf[16*TPB*DD];        // 64 KB partials (A, B, C reuse)
  __shared__ float red[TPB][2][2];
  __shared__ float fm1[DD], fm2[DD];
  __shared__ int   fam[DD];
  __shared__ float sm1[4][DD], sm2[4][DD];
  __shared__ int   sam[4][DD];

  // ---- merge the batch's npart pool partials (npart/4 per fourth) ----
  {
    int per = npart >> 2;
    size_t base = ((size_t)b*npart + fourth*per)*DD + d;
    float m1 = pm1p[base], m2 = pm2p[base]; int am = pargp[base];
    for (int i=1;i<per;++i)
      poolMerge(m1,m2,am, pm1p[base+(size_t)i*DD], pm2p[base+(size_t)i*DD],
                pargp[base+(size_t)i*DD]);
    sm1[fourth][d]=m1; sm2[fourth][d]=m2; sam[fourth][d]=am;
  }
  __syncthreads();
  if (fourth==0){
    float m1=sm1[0][d], m2=sm2[0][d]; int am=sam[0][d];
    #pragma unroll
    for (int p=1;p<4;++p) poolMerge(m1,m2,am, sm1[p][d], sm2[p][d], sam[p][d]);
    fm1[d]=m1; fm2[d]=m2; fam[d]=am;
  }
  __syncthreads();

  // ---- build cat[8][256]: 4 entries per thread, wave-uniform branch ----
  #pragma unroll
  for (int rep=0; rep<4; ++rep){
    int e = rep*512 + tid;
    int t = e >> 8, c = e & 255;
    int tok = t0 + t, n = (t0 & 255) + t;
    float v;
    if (c < DD) v = h[(size_t)tok*DD + c];
    else { int cc = c - DD; v = (n==fam[cc]) ? fm2[cc] : fm1[cc]; }
    cat[t][c] = v;
  }
  __syncthreads();

  // ---- stage A: y[4q..4q+3] partial over k in [16p,16p+16) ----
  {
    int q = tid & 31, p = tid >> 5;
    float4 acc[TPB];
    #pragma unroll
    for (int t=0;t<TPB;++t) acc[t] = make_float4(0.f,0.f,0.f,0.f);
    const ushort_t* wp = Wp + 4*q;
    int k0 = p*16;
    #pragma unroll
    for (int kk=0; kk<16; ++kk){
      int k = k0 + kk;
      uint2 wb = *(const uint2*)&wp[(size_t)k*DD];
      float w0,w1,w2,w3; unp4(wb,w0,w1,w2,w3);
      #pragma unroll
      for (int t=0;t<TPB;++t){
        float c = cat[t][k];
        acc[t].x = fmaf(c, w0, acc[t].x);
        acc[t].y = fmaf(c, w1, acc[t].y);
        acc[t].z = fmaf(c, w2, acc[t].z);
        acc[t].w = fmaf(c, w3, acc[t].w);
      }
    }
    #pragma unroll
    for (int t=0;t<TPB;++t)
      *(float4*)&pf[((p*TPB)+t)*DD + 4*q] = acc[t];
  }
  __syncthreads();

  // ---- combine A: sum 16 partials + bias + residual, LN -> h1s ----
  {
    float vv[2];
    #pragma unroll
    for (int tt=0;tt<2;++tt){
      int t = fourth*2 + tt;
      float v = 0.f;
      #pragma unroll
      for (int p=0;p<16;++p) v += pf[((p*TPB)+t)*DD + d];
      v += bp[d] + cat[t][d];
      vv[tt] = v;
      float s=v,q=v*v; waveRed2(s,q);
      if (lane==0){ red[t][wid][0]=s; red[t][wid][1]=q; }
    }
    __syncthreads();
    #pragma unroll
    for (int tt=0;tt<2;++tt){
      int t = fourth*2 + tt;
      float S=red[t][0][0]+red[t][1][0], Q=red[t][0][1]+red[t][1][1];
      float m=S*(1.f/DD), var=Q*(1.f/DD)-m*m, rs=rsqrtf(var+EPSV);
      h1s[t][d] = (vv[tt]-m)*rs*gp[d] + bgp[d];
    }
  }
  __syncthreads();

  // ---- stage B: u[4J..4J+3] partial over k in [32p,32p+32) ----
  {
    int J = tid & 127, p = tid >> 7;
    float4 acc[TPB];
    #pragma unroll
    for (int t=0;t<TPB;++t) acc[t] = make_float4(0.f,0.f,0.f,0.f);
    const ushort_t* w1p = W1 + 4*J;
    int k0 = p*32;
    #pragma unroll 8
    for (int kk=0; kk<32; ++kk){
      int k = k0 + kk;
      uint2 wb = *(const uint2*)&w1p[(size_t)k*HH];
      float w0,w1,w2,w3; unp4(wb,w0,w1,w2,w3);
      #pragma unroll
      for (int t=0;t<TPB;++t){
        float c = h1s[t][k];
        acc[t].x = fmaf(c, w0, acc[t].x);
        acc[t].y = fmaf(c, w1, acc[t].y);
        acc[t].z = fmaf(c, w2, acc[t].z);
        acc[t].w = fmaf(c, w3, acc[t].w);
      }
    }
    #pragma unroll
    for (int t=0;t<TPB;++t)
      *(float4*)&pf[((p*TPB)+t)*HH + 4*J] = acc[t];
  }
  __syncthreads();

  // ---- combine B: sum 4 partials + bias, relu -> us ----
  {
    int j = tid;
    float b1v = b1[j];
    #pragma unroll
    for (int t=0;t<TPB;++t){
      float v = pf[((0*TPB)+t)*HH + j] + pf[((1*TPB)+t)*HH + j]
              + pf[((2*TPB)+t)*HH + j] + pf[((3*TPB)+t)*HH + j];
      us[t][j] = fmaxf(v + b1v, 0.f);
    }
  }
  __syncthreads();

  // ---- stage C: z[4q..4q+3] partial over j in [32p,32p+32) ----
  {
    int q = tid & 31, p = tid >> 5;
    float4 acc[TPB];
    #pragma unroll
    for (int t=0;t<TPB;++t) acc[t] = make_float4(0.f,0.f,0.f,0.f);
    const ushort_t* w2p = W2 + 4*q;
    int j0 = p*32;
    #pragma unroll 8
    for (int jj=0; jj<32; ++jj){
      int j = j0 + jj;
      uint2 wb = *(const uint2*)&w2p[(size_t)j*DD];
      float w0,w1,w2,w3; unp4(wb,w0,w1,w2,w3);
      #pragma unroll
      for (int t=0;t<TPB;++t){
        float c = us[t][j];
        acc[t].x = fmaf(c, w0, acc[t].x);
        acc[t].y = fmaf(c, w1, acc[t].y);
        acc[t].z = fmaf(c, w2, acc[t].z);
        acc[t].w = fmaf(c, w3, acc[t].w);
      }
    }
    __syncthreads();    // combine-B pf reads done before overwrite
    #pragma unroll
    for (int t=0;t<TPB;++t)
      *(float4*)&pf[((p*TPB)+t)*DD + 4*q] = acc[t];
  }
  __syncthreads();

  // ---- combine C: sum 16 partials + bias + residual, LN -> h + pool ----
  {
    float vv[2];
    #pragma unroll
    for (int tt=0;tt<2;++tt){
      int t = fourth*2 + tt;
      float v = 0.f;
      #pragma unroll
      for (int p=0;p<16;++p) v += pf[((p*TPB)+t)*DD + d];
      v += b2[d] + h1s[t][d];
      vv[tt] = v;
      float s=v,q=v*v; waveRed2(s,q);
      if (lane==0){ red[t][wid][0]=s; red[t][wid][1]=q; }
    }
    __syncthreads();
    #pragma unroll
    for (int tt=0;tt<2;++tt){
      int t = fourth*2 + tt;
      float S=red[t][0][0]+red[t][1][0], Q=red[t][0][1]+red[t][1][1];
      float m=S*(1.f/DD), var=Q*(1.f/DD)-m*m, rs=rsqrtf(var+EPSV);
      float hv = (vv[tt]-m)*rs*gf[d] + bgf[d];
      h[(size_t)(t0+t)*DD + d] = hv;
      cat[t][d] = hv;
    }
  }
  if (write_pool){
    __syncthreads();
    if (fourth==0){
      int n0 = t0 & 255;
      float m1 = cat[0][d], m2=-3.4e38f; int am=n0;
      #pragma unroll
      for (int p=1;p<TPB;++p) poolMerge(m1,m2,am, cat[p][d], -3.4e38f, n0+p);
      int blk = (t0>>3)&(BPL-1);
      size_t idx = ((size_t)b*BPL+blk)*DD + d;
      qm1p[idx]=m1; qm2p[idx]=m2; qargp[idx]=am;
    }
  }
}

extern "C" void kernel_launch(void* const* d_in, const int* in_sizes, int n_in,
                              void* d_out, int out_size, void* d_ws, size_t ws_size,
                              hipStream_t stream)
{
  const float* x   = (const float*)d_in[0];
  const float* We  = (const float*)d_in[1];
  const float* be  = (const float*)d_in[2];
  const float* ge  = (const float*)d_in[3];
  const float* bge = (const float*)d_in[4];
  const float* Wp  = (const float*)d_in[5];
  const float* bp  = (const float*)d_in[6];
  const float* gp  = (const float*)d_in[7];
  const float* bgp = (const float*)d_in[8];
  const float* W1  = (const float*)d_in[9];
  const float* b1  = (const float*)d_in[10];
  const float* W2  = (const float*)d_in[11];
  const float* b2  = (const float*)d_in[12];
  const float* gf  = (const float*)d_in[13];
  const float* bgf = (const float*)d_in[14];

  // h lives in d_out; final layer's in-place update IS the output.
  float* h = (float*)d_out;
  char* ws = (char*)d_ws;
  const size_t NA = (size_t)BB*BPE*DD;       // 65536 embed partial entries
  const size_t NB = (size_t)BB*BPL*DD;       // 32768 layer partial entries
  float* pA1 = (float*)ws;                    ws += NA*4;
  float* pA2 = (float*)ws;                    ws += NA*4;
  int*   pAa = (int*)ws;                      ws += NA*4;
  float* pB1 = (float*)ws;                    ws += NB*4;
  float* pB2 = (float*)ws;                    ws += NB*4;
  int*   pBa = (int*)ws;                      ws += NB*4;
  ushort_t* wpb = (ushort_t*)ws;              ws += (size_t)LL*2*DD*DD*2;
  ushort_t* w1b = (ushort_t*)ws;              ws += (size_t)LL*DD*HH*2;
  ushort_t* w2b = (ushort_t*)ws;              ws += (size_t)LL*HH*DD*2;

  const int NCONV = LL*(2*DD*DD + DD*HH + HH*DD);   // 327680
  k_conv<<<NCONV/512, 512, 0, stream>>>(Wp, W1, W2, wpb, w1b, w2b);

  k_embed<<<(BB*NN)/TPE, 512, 0, stream>>>(x, We, be, ge, bge, h, pA1, pA2, pAa);

  k_layer<<<(BB*NN)/TPB, 512, 0, stream>>>(h, pA1, pA2, pAa, BPE,
      pB1, pB2, pBa, 1,
      wpb,                    bp,       gp,       bgp,
      w1b,                    b1,       w2b,      b2,
      gf,                     bgf);

  k_layer<<<(BB*NN)/TPB, 512, 0, stream>>>(h, pB1, pB2, pBa, BPL,
      pB1, pB2, pBa, 0,
      wpb + (size_t)2*DD*DD,  bp + DD,  gp + DD,  bgp + DD,
      w1b + (size_t)DD*HH,    b1 + HH,  w2b + (size_t)HH*DD, b2 + DD,
      gf + DD,                bgf + DD);
}

// Round 8
// 123.177 us; speedup vs baseline: 1.0819x; 1.0151x over previous
//
#include <hip/hip_runtime.h>
#include <hip/hip_bf16.h>

#define BB 8
#define NN 256
#define DD 128
#define HH 512
#define LL 2
#define EPSV 1e-5f
#define TPE 4            // tokens per block in k_embed
#define TPB 8            // tokens per block in k_layer
#define BPE (NN/TPE)     // embed pool partials per batch = 64
#define BPL (NN/TPB)     // layer pool partials per batch = 32

typedef unsigned short ushort_t;
typedef __attribute__((ext_vector_type(8))) short bf16x8;
typedef __attribute__((ext_vector_type(4))) float f32x4;

__device__ __forceinline__ ushort_t f2b(float v){
  __hip_bfloat16 h = __float2bfloat16(v);
  return *(ushort_t*)&h;
}

__device__ __forceinline__ void waveRed2(float &a, float &b){
  #pragma unroll
  for (int off=32; off>=1; off>>=1){
    a += __shfl_xor(a, off, 64);
    b += __shfl_xor(b, off, 64);
  }
}

__device__ __forceinline__ void poolMerge(float &m1, float &m2, int &am,
                                          float o1, float o2, int oa){
  if (o1 > m1){ m2 = fmaxf(m1, o2); m1 = o1; am = oa; }
  else        { m2 = fmaxf(m2, o1); }
}

// ---- weight f32 -> bf16 TRANSPOSE to [N][K] (B-fragment friendly) ----
// 320 tile-blocks of 32x32, 256 threads each.
__global__ __launch_bounds__(256) void k_conv(
    const float* __restrict__ Wp, const float* __restrict__ W1,
    const float* __restrict__ W2, ushort_t* __restrict__ wpT,
    ushort_t* __restrict__ w1T, ushort_t* __restrict__ w2T)
{
  __shared__ float tile[32][33];
  int bid = blockIdx.x;
  const float* src; ushort_t* dst; int K, N, kt, nt;
  if (bid < 64){                       // Wp: [256][128] -> [128][256]
    int l = bid >> 5, r = bid & 31;
    src = Wp + (size_t)l*256*128; dst = wpT + (size_t)l*128*256;
    K=256; N=128; kt = r >> 2; nt = r & 3;
  } else if (bid < 192){               // W1: [128][512] -> [512][128]
    int e = bid - 64; int l = e >> 6, r = e & 63;
    src = W1 + (size_t)l*128*512; dst = w1T + (size_t)l*512*128;
    K=128; N=512; kt = r >> 4; nt = r & 15;
  } else {                             // W2: [512][128] -> [128][512]
    int e = bid - 192; int l = e >> 6, r = e & 63;
    src = W2 + (size_t)l*512*128; dst = w2T + (size_t)l*128*512;
    K=512; N=128; kt = r >> 2; nt = r & 3;
  }
  int k0 = kt*32, n0 = nt*32;
  int tx = threadIdx.x & 31, ty = threadIdx.x >> 5;
  #pragma unroll
  for (int i=0;i<4;++i)
    tile[ty + i*8][tx] = src[(size_t)(k0+ty+i*8)*N + n0 + tx];
  __syncthreads();
  #pragma unroll
  for (int i=0;i<4;++i)
    dst[(size_t)(n0+ty+i*8)*K + k0 + tx] = f2b(tile[tx][ty + i*8]);
}

// ---- embed + LN + pool-partial: 512 thr = (token 0..3) x (d 0..127) ----
__global__ __launch_bounds__(512) void k_embed(
    const float* __restrict__ x, const float* __restrict__ We,
    const float* __restrict__ be, const float* __restrict__ ge,
    const float* __restrict__ bge, float* __restrict__ h,
    float* __restrict__ pm1p, float* __restrict__ pm2p, int* __restrict__ pargp)
{
  int tid = threadIdx.x;
  int t = tid >> 7, d = tid & 127;
  int lane = tid & 63, wid = (tid >> 6) & 1;
  int t0 = blockIdx.x * TPE;
  int tok = t0 + t;
  __shared__ float red[TPE][2][2];
  __shared__ float hf[TPE][DD];
  float x0 = x[tok*2], x1 = x[tok*2+1];
  float v = fmaf(x0, We[d], fmaf(x1, We[DD+d], be[d]));
  float s=v, q=v*v; waveRed2(s,q);
  if (lane==0){ red[t][wid][0]=s; red[t][wid][1]=q; }
  __syncthreads();
  float S=red[t][0][0]+red[t][1][0], Q=red[t][0][1]+red[t][1][1];
  float m=S*(1.f/DD), var=Q*(1.f/DD)-m*m, rs=rsqrtf(var+EPSV);
  float hv = (v-m)*rs*ge[d] + bge[d];
  h[(size_t)tok*DD + d] = hv;
  hf[t][d] = hv;
  __syncthreads();
  if (t==0){
    int b = t0 >> 8;
    int n0 = t0 & 255;
    float m1 = hf[0][d], m2 = -3.4e38f; int am = n0;
    #pragma unroll
    for (int p=1;p<TPE;++p) poolMerge(m1,m2,am, hf[p][d], -3.4e38f, n0+p);
    int blk = (t0 >> 2) & (BPE-1);
    size_t idx = ((size_t)b*BPE + blk)*DD + d;
    pm1p[idx]=m1; pm2p[idx]=m2; pargp[idx]=am;
  }
}

// ---- fused layer, MFMA 16x16x32 bf16. 512 thr = 8 waves, TPB=8 tokens
// (rows 8..15 of the M=16 tile are junk; rows don't mix in D=A*B, and all
// epilogues read rows 0..7 only). Weights pre-transposed [N][K] bf16 so a
// B-fragment is one 16-B global load; activations staged in LDS bf16 [m][k]
// so an A-fragment is one ds_read_b128. h updated in place (h == d_out).
__global__ __launch_bounds__(512) void k_layer(
    float* __restrict__ h,
    const float* __restrict__ pm1p, const float* __restrict__ pm2p,
    const int* __restrict__ pargp, int npart,
    float* __restrict__ qm1p, float* __restrict__ qm2p, int* __restrict__ qargp,
    int write_pool,
    const ushort_t* __restrict__ WpT, const float* __restrict__ bp,
    const float* __restrict__ gp, const float* __restrict__ bgp,
    const ushort_t* __restrict__ W1T, const float* __restrict__ b1,
    const ushort_t* __restrict__ W2T, const float* __restrict__ b2,
    const float* __restrict__ gf, const float* __restrict__ bgf)
{
  int tid = threadIdx.x;
  int d = tid & 127, fourth = tid >> 7;
  int wv = tid >> 6;            // wave 0..7
  int lane = tid & 63;
  int m = lane & 15, q = lane >> 4;
  int t0 = blockIdx.x * TPB;
  int b = t0 >> 8;

  __shared__ ushort_t catb[16*256];   // 8K  bf16 A-operand, stage A
  __shared__ float    hres[8*128];    // 4K  stage-A residual (reused: hfin)
  __shared__ float    sA[16*128];     // 8K  f32 GEMM out (A, then C)
  __shared__ ushort_t h1b[16*128];    // 4K  bf16 A-operand, stage B
  __shared__ float    h1f[8*128];     // 4K  f32 h1 for stage-C residual
  __shared__ ushort_t ub[16*512];     // 16K bf16 A-operand, stage C
  __shared__ float fm1[128], fm2[128];
  __shared__ int   fam[128];
  __shared__ float sm1[4][128], sm2[4][128];
  __shared__ int   sam[4][128];

  // ---- prologue: merge the batch's npart pool partials ----
  {
    int per = npart >> 2;
    size_t base = ((size_t)b*npart + fourth*per)*DD + d;
    float m1 = pm1p[base], m2 = pm2p[base]; int am = pargp[base];
    for (int i=1;i<per;++i)
      poolMerge(m1,m2,am, pm1p[base+(size_t)i*DD], pm2p[base+(size_t)i*DD],
                pargp[base+(size_t)i*DD]);
    sm1[fourth][d]=m1; sm2[fourth][d]=m2; sam[fourth][d]=am;
  }
  __syncthreads();
  if (fourth==0){
    float m1=sm1[0][d], m2=sm2[0][d]; int am=sam[0][d];
    #pragma unroll
    for (int p=1;p<4;++p) poolMerge(m1,m2,am, sm1[p][d], sm2[p][d], sam[p][d]);
    fm1[d]=m1; fm2[d]=m2; fam[d]=am;
  }
  __syncthreads();

  // ---- cat build: catb[8][256] bf16 + hres f32 ----
  #pragma unroll
  for (int rep=0; rep<4; ++rep){
    int e = rep*512 + tid;
    int t = e >> 8, c = e & 255;
    int tok = t0 + t, n = (t0 & 255) + t;
    float v;
    if (c < DD){ v = h[(size_t)tok*DD + c]; hres[t*128 + c] = v; }
    else { int cc = c - DD; v = (n==fam[cc]) ? fm2[cc] : fm1[cc]; }
    catb[t*256 + c] = f2b(v);
  }
  __syncthreads();

  // ---- stage A: [16 x 128] = cat[16 x 256] @ Wp ----
  {
    int n0 = wv*16;
    f32x4 acc = {0.f,0.f,0.f,0.f};
    const ushort_t* ap = catb + m*256 + q*8;
    const ushort_t* wp = WpT + (size_t)(n0+m)*256 + q*8;
    #pragma unroll
    for (int ks=0; ks<8; ++ks){
      bf16x8 af = *(const bf16x8*)(ap + ks*32);
      bf16x8 wf = *(const bf16x8*)(wp + ks*32);
      acc = __builtin_amdgcn_mfma_f32_16x16x32_bf16(af, wf, acc, 0,0,0);
    }
    #pragma unroll
    for (int r=0;r<4;++r) sA[(q*4+r)*128 + n0 + m] = acc[r];
  }
  __syncthreads();

  // ---- LN-A: wave t = token t; lane handles d = 2g, 2g+1 ----
  {
    int t = wv, g = lane;
    float2 v2 = *(const float2*)&sA[t*128 + 2*g];
    float v0 = v2.x + bp[2*g]   + hres[t*128 + 2*g];
    float v1 = v2.y + bp[2*g+1] + hres[t*128 + 2*g + 1];
    float s = v0+v1, qq = v0*v0 + v1*v1;
    waveRed2(s,qq);
    float mean = s*(1.f/128), var = qq*(1.f/128) - mean*mean;
    float rs = rsqrtf(var + EPSV);
    float o0 = (v0-mean)*rs*gp[2*g]   + bgp[2*g];
    float o1 = (v1-mean)*rs*gp[2*g+1] + bgp[2*g+1];
    unsigned pk = (unsigned)f2b(o0) | ((unsigned)f2b(o1) << 16);
    *(unsigned*)&h1b[t*128 + 2*g] = pk;
    *(float2*)&h1f[t*128 + 2*g] = make_float2(o0, o1);
  }
  __syncthreads();

  // ---- stage B: [16 x 512] = h1[16 x 128] @ W1, 4 col-tiles/wave ----
  {
    const ushort_t* ap = h1b + m*128 + q*8;
    #pragma unroll
    for (int i=0;i<4;++i){
      int n0 = i*128 + wv*16;
      f32x4 acc = {0.f,0.f,0.f,0.f};
      const ushort_t* wp = W1T + (size_t)(n0+m)*128 + q*8;
      #pragma unroll
      for (int ks=0; ks<4; ++ks){
        bf16x8 af = *(const bf16x8*)(ap + ks*32);
        bf16x8 wf = *(const bf16x8*)(wp + ks*32);
        acc = __builtin_amdgcn_mfma_f32_16x16x32_bf16(af, wf, acc, 0,0,0);
      }
      float bb = b1[n0+m];
      #pragma unroll
      for (int r=0;r<4;++r)
        ub[(q*4+r)*512 + n0 + m] = f2b(fmaxf(acc[r] + bb, 0.f));
    }
  }
  __syncthreads();

  // ---- stage C: [16 x 128] = u[16 x 512] @ W2 ----
  {
    int n0 = wv*16;
    f32x4 acc = {0.f,0.f,0.f,0.f};
    const ushort_t* ap = ub + m*512 + q*8;
    const ushort_t* wp = W2T + (size_t)(n0+m)*512 + q*8;
    #pragma unroll
    for (int ks=0; ks<16; ++ks){
      bf16x8 af = *(const bf16x8*)(ap + ks*32);
      bf16x8 wf = *(const bf16x8*)(wp + ks*32);
      acc = __builtin_amdgcn_mfma_f32_16x16x32_bf16(af, wf, acc, 0,0,0);
    }
    #pragma unroll
    for (int r=0;r<4;++r) sA[(q*4+r)*128 + n0 + m] = acc[r];
  }
  __syncthreads();

  // ---- LN-C: residual h1f, write h (global) + hfin (pool) ----
  {
    int t = wv, g = lane;
    float2 v2 = *(const float2*)&sA[t*128 + 2*g];
    float v0 = v2.x + b2[2*g]   + h1f[t*128 + 2*g];
    float v1 = v2.y + b2[2*g+1] + h1f[t*128 + 2*g + 1];
    float s = v0+v1, qq = v0*v0 + v1*v1;
    waveRed2(s,qq);
    float mean = s*(1.f/128), var = qq*(1.f/128) - mean*mean;
    float rs = rsqrtf(var + EPSV);
    float o0 = (v0-mean)*rs*gf[2*g]   + bgf[2*g];
    float o1 = (v1-mean)*rs*gf[2*g+1] + bgf[2*g+1];
    *(float2*)&h[(size_t)(t0+t)*DD + 2*g] = make_float2(o0, o1);
    *(float2*)&hres[t*128 + 2*g] = make_float2(o0, o1);   // hfin
  }
  if (write_pool){
    __syncthreads();
    if (tid < 128){
      int n0 = t0 & 255;
      float m1 = hres[tid], m2 = -3.4e38f; int am = n0;
      #pragma unroll
      for (int p=1;p<TPB;++p)
        poolMerge(m1,m2,am, hres[p*128 + tid], -3.4e38f, n0+p);
      int blk = (t0 >> 3) & (BPL-1);
      size_t idx = ((size_t)b*BPL + blk)*DD + tid;
      qm1p[idx]=m1; qm2p[idx]=m2; qargp[idx]=am;
    }
  }
}

extern "C" void kernel_launch(void* const* d_in, const int* in_sizes, int n_in,
                              void* d_out, int out_size, void* d_ws, size_t ws_size,
                              hipStream_t stream)
{
  const float* x   = (const float*)d_in[0];
  const float* We  = (const float*)d_in[1];
  const float* be  = (const float*)d_in[2];
  const float* ge  = (const float*)d_in[3];
  const float* bge = (const float*)d_in[4];
  const float* Wp  = (const float*)d_in[5];
  const float* bp  = (const float*)d_in[6];
  const float* gp  = (const float*)d_in[7];
  const float* bgp = (const float*)d_in[8];
  const float* W1  = (const float*)d_in[9];
  const float* b1  = (const float*)d_in[10];
  const float* W2  = (const float*)d_in[11];
  const float* b2  = (const float*)d_in[12];
  const float* gf  = (const float*)d_in[13];
  const float* bgf = (const float*)d_in[14];

  // h lives in d_out; final layer's in-place update IS the output.
  float* h = (float*)d_out;
  char* ws = (char*)d_ws;
  const size_t NA = (size_t)BB*BPE*DD;       // 65536
  const size_t NB = (size_t)BB*BPL*DD;       // 32768
  float* pA1 = (float*)ws;                    ws += NA*4;
  float* pA2 = (float*)ws;                    ws += NA*4;
  int*   pAa = (int*)ws;                      ws += NA*4;
  float* pB1 = (float*)ws;                    ws += NB*4;
  float* pB2 = (float*)ws;                    ws += NB*4;
  int*   pBa = (int*)ws;                      ws += NB*4;
  ushort_t* wpT = (ushort_t*)ws;              ws += (size_t)LL*DD*2*DD*2;
  ushort_t* w1T = (ushort_t*)ws;              ws += (size_t)LL*HH*DD*2;
  ushort_t* w2T = (ushort_t*)ws;              ws += (size_t)LL*DD*HH*2;

  k_conv<<<320, 256, 0, stream>>>(Wp, W1, W2, wpT, w1T, w2T);

  k_embed<<<(BB*NN)/TPE, 512, 0, stream>>>(x, We, be, ge, bge, h, pA1, pA2, pAa);

  k_layer<<<(BB*NN)/TPB, 512, 0, stream>>>(h, pA1, pA2, pAa, BPE,
      pB1, pB2, pBa, 1,
      wpT,                     bp,       gp,       bgp,
      w1T,                     b1,       w2T,      b2,
      gf,                      bgf);

  k_layer<<<(BB*NN)/TPB, 512, 0, stream>>>(h, pB1, pB2, pBa, BPL,
      pB1, pB2, pBa, 0,
      wpT + (size_t)DD*2*DD,   bp + DD,  gp + DD,  bgp + DD,
      w1T + (size_t)HH*DD,     b1 + HH,  w2T + (size_t)DD*HH, b2 + DD,
      gf + DD,                 bgf + DD);
}

// Round 9
// 123.099 us; speedup vs baseline: 1.0826x; 1.0006x over previous
//
#include <hip/hip_runtime.h>
#include <hip/hip_bf16.h>

#define BB 8
#define NN 256
#define DD 128
#define HH 512
#define LL 2
#define EPSV 1e-5f
#define TPE 4            // tokens per block in embed part of k_prep
#define TPB 8            // tokens per block in k_layer
#define BPE (NN/TPE)     // embed pool partials per batch = 64
#define BPL (NN/TPB)     // layer pool partials per batch = 32
#define NEMB ((BB*NN)/TPE)   // 512 embed blocks

typedef unsigned short ushort_t;
typedef __attribute__((ext_vector_type(8))) short bf16x8;
typedef __attribute__((ext_vector_type(4))) float f32x4;

__device__ __forceinline__ ushort_t f2b(float v){
  __hip_bfloat16 h = __float2bfloat16(v);
  return *(ushort_t*)&h;
}

__device__ __forceinline__ void waveRed2(float &a, float &b){
  #pragma unroll
  for (int off=32; off>=1; off>>=1){
    a += __shfl_xor(a, off, 64);
    b += __shfl_xor(b, off, 64);
  }
}

__device__ __forceinline__ void poolMerge(float &m1, float &m2, int &am,
                                          float o1, float o2, int oa){
  if (o1 > m1){ m2 = fmaxf(m1, o2); m1 = o1; am = oa; }
  else        { m2 = fmaxf(m2, o1); }
}

// ---- merged prep: embed+LN+pool-partial (blocks 0..511) and
//      weight f32->bf16 transpose to [N][K] (blocks 512..831) ----
__global__ __launch_bounds__(512) void k_prep(
    const float* __restrict__ x, const float* __restrict__ We,
    const float* __restrict__ be, const float* __restrict__ ge,
    const float* __restrict__ bge, float* __restrict__ h,
    float* __restrict__ pm1p, float* __restrict__ pm2p, int* __restrict__ pargp,
    const float* __restrict__ Wp, const float* __restrict__ W1,
    const float* __restrict__ W2, ushort_t* __restrict__ wpT,
    ushort_t* __restrict__ w1T, ushort_t* __restrict__ w2T)
{
  __shared__ float tile[32][33];
  __shared__ float red[TPE][2][2];
  __shared__ float hf[TPE][DD];

  if (blockIdx.x < NEMB){
    // ---------------- embed + LN + pool partial ----------------
    int tid = threadIdx.x;
    int t = tid >> 7, d = tid & 127;
    int lane = tid & 63, wid = (tid >> 6) & 1;
    int t0 = blockIdx.x * TPE;
    int tok = t0 + t;
    float x0 = x[tok*2], x1 = x[tok*2+1];
    float v = fmaf(x0, We[d], fmaf(x1, We[DD+d], be[d]));
    float s=v, q=v*v; waveRed2(s,q);
    if (lane==0){ red[t][wid][0]=s; red[t][wid][1]=q; }
    __syncthreads();
    float S=red[t][0][0]+red[t][1][0], Q=red[t][0][1]+red[t][1][1];
    float m=S*(1.f/DD), var=Q*(1.f/DD)-m*m, rs=rsqrtf(var+EPSV);
    float hv = (v-m)*rs*ge[d] + bge[d];
    h[(size_t)tok*DD + d] = hv;
    hf[t][d] = hv;
    __syncthreads();
    if (t==0){
      int b = t0 >> 8;
      int n0 = t0 & 255;
      float m1 = hf[0][d], m2 = -3.4e38f; int am = n0;
      #pragma unroll
      for (int p=1;p<TPE;++p) poolMerge(m1,m2,am, hf[p][d], -3.4e38f, n0+p);
      int blk = (t0 >> 2) & (BPE-1);
      size_t idx = ((size_t)b*BPE + blk)*DD + d;
      pm1p[idx]=m1; pm2p[idx]=m2; pargp[idx]=am;
    }
  } else {
    // ---------------- weight transpose+pack (256 active thr) ----------------
    if (threadIdx.x >= 256) return;
    int bid = blockIdx.x - NEMB;
    const float* src; ushort_t* dst; int K, N, kt, nt;
    if (bid < 64){                       // Wp: [256][128] -> [128][256]
      int l = bid >> 5, r = bid & 31;
      src = Wp + (size_t)l*256*128; dst = wpT + (size_t)l*128*256;
      K=256; N=128; kt = r >> 2; nt = r & 3;
    } else if (bid < 192){               // W1: [128][512] -> [512][128]
      int e = bid - 64; int l = e >> 6, r = e & 63;
      src = W1 + (size_t)l*128*512; dst = w1T + (size_t)l*512*128;
      K=128; N=512; kt = r >> 4; nt = r & 15;
    } else {                             // W2: [512][128] -> [128][512]
      int e = bid - 192; int l = e >> 6, r = e & 63;
      src = W2 + (size_t)l*512*128; dst = w2T + (size_t)l*128*512;
      K=512; N=128; kt = r >> 2; nt = r & 3;
    }
    int k0 = kt*32, n0 = nt*32;
    int tx = threadIdx.x & 31, ty = threadIdx.x >> 5;
    #pragma unroll
    for (int i=0;i<4;++i)
      tile[ty + i*8][tx] = src[(size_t)(k0+ty+i*8)*N + n0 + tx];
    __syncthreads();
    #pragma unroll
    for (int i=0;i<4;++i)
      dst[(size_t)(n0+ty+i*8)*K + k0 + tx] = f2b(tile[tx][ty + i*8]);
  }
}

// ---- fused layer, MFMA 16x16x32 bf16, batch-issued weight fragments.
// 512 thr = 8 waves, TPB=8 tokens (tile rows 8..15 junk, never read).
// Stage-A and stage-B weight fragments are loaded into registers AT KERNEL
// TOP (independent of all prior work) so their L2 latency overlaps the pool
// merge + cat build; stage-C fragments load right after stage A's MFMAs.
__global__ __launch_bounds__(512, 2) void k_layer(
    float* __restrict__ h,
    const float* __restrict__ pm1p, const float* __restrict__ pm2p,
    const int* __restrict__ pargp, int npart,
    float* __restrict__ qm1p, float* __restrict__ qm2p, int* __restrict__ qargp,
    int write_pool,
    const ushort_t* __restrict__ WpT, const float* __restrict__ bp,
    const float* __restrict__ gp, const float* __restrict__ bgp,
    const ushort_t* __restrict__ W1T, const float* __restrict__ b1,
    const ushort_t* __restrict__ W2T, const float* __restrict__ b2,
    const float* __restrict__ gf, const float* __restrict__ bgf)
{
  int tid = threadIdx.x;
  int d = tid & 127, fourth = tid >> 7;
  int wv = tid >> 6;            // wave 0..7
  int lane = tid & 63;
  int m = lane & 15, q = lane >> 4;
  int t0 = blockIdx.x * TPB;
  int b = t0 >> 8;

  __shared__ ushort_t catb[16*256];   // 8K  bf16 A-operand, stage A
  __shared__ float    hres[8*128];    // 4K  stage-A residual (reused: hfin)
  __shared__ float    sA[16*128];     // 8K  f32 GEMM out (A, then C)
  __shared__ ushort_t h1b[16*128];    // 4K  bf16 A-operand, stage B
  __shared__ float    h1f[8*128];     // 4K  f32 h1 for stage-C residual
  __shared__ ushort_t ub[16*512];     // 16K bf16 A-operand, stage C
  __shared__ float fm1[128], fm2[128];
  __shared__ int   fam[128];
  __shared__ float sm1[4][128], sm2[4][128];
  __shared__ int   sam[4][128];

  // ---- batch-issue stage A + stage B weight fragments (no dependencies) ----
  int n0a = wv*16;
  bf16x8 wfA[8];
  {
    const ushort_t* wp = WpT + (size_t)(n0a+m)*256 + q*8;
    #pragma unroll
    for (int ks=0; ks<8; ++ks) wfA[ks] = *(const bf16x8*)(wp + ks*32);
  }
  bf16x8 wfB[16];
  {
    #pragma unroll
    for (int i=0;i<4;++i){
      int n0 = i*128 + wv*16;
      const ushort_t* wp = W1T + (size_t)(n0+m)*128 + q*8;
      #pragma unroll
      for (int ks=0; ks<4; ++ks) wfB[i*4+ks] = *(const bf16x8*)(wp + ks*32);
    }
  }

  // ---- prologue: merge the batch's npart pool partials ----
  {
    int per = npart >> 2;
    size_t base = ((size_t)b*npart + fourth*per)*DD + d;
    float m1 = pm1p[base], m2 = pm2p[base]; int am = pargp[base];
    for (int i=1;i<per;++i)
      poolMerge(m1,m2,am, pm1p[base+(size_t)i*DD], pm2p[base+(size_t)i*DD],
                pargp[base+(size_t)i*DD]);
    sm1[fourth][d]=m1; sm2[fourth][d]=m2; sam[fourth][d]=am;
  }
  __syncthreads();
  if (fourth==0){
    float m1=sm1[0][d], m2=sm2[0][d]; int am=sam[0][d];
    #pragma unroll
    for (int p=1;p<4;++p) poolMerge(m1,m2,am, sm1[p][d], sm2[p][d], sam[p][d]);
    fm1[d]=m1; fm2[d]=m2; fam[d]=am;
  }
  __syncthreads();

  // ---- cat build: catb[8][256] bf16 + hres f32 ----
  #pragma unroll
  for (int rep=0; rep<4; ++rep){
    int e = rep*512 + tid;
    int t = e >> 8, c = e & 255;
    int tok = t0 + t, n = (t0 & 255) + t;
    float v;
    if (c < DD){ v = h[(size_t)tok*DD + c]; hres[t*128 + c] = v; }
    else { int cc = c - DD; v = (n==fam[cc]) ? fm2[cc] : fm1[cc]; }
    catb[t*256 + c] = f2b(v);
  }
  __syncthreads();

  // ---- stage A: [16 x 128] = cat[16 x 256] @ Wp (weights in regs) ----
  {
    f32x4 acc = {0.f,0.f,0.f,0.f};
    const ushort_t* ap = catb + m*256 + q*8;
    #pragma unroll
    for (int ks=0; ks<8; ++ks){
      bf16x8 af = *(const bf16x8*)(ap + ks*32);
      acc = __builtin_amdgcn_mfma_f32_16x16x32_bf16(af, wfA[ks], acc, 0,0,0);
    }
    #pragma unroll
    for (int r=0;r<4;++r) sA[(q*4+r)*128 + n0a + m] = acc[r];
  }

  // ---- batch-issue stage C weight fragments (hide behind LN-A + stage B) ----
  bf16x8 wfC[16];
  {
    const ushort_t* wp = W2T + (size_t)(n0a+m)*512 + q*8;
    #pragma unroll
    for (int ks=0; ks<16; ++ks) wfC[ks] = *(const bf16x8*)(wp + ks*32);
  }
  __syncthreads();

  // ---- LN-A: wave t = token t; lane handles d = 2g, 2g+1 ----
  {
    int t = wv, g = lane;
    float2 v2 = *(const float2*)&sA[t*128 + 2*g];
    float v0 = v2.x + bp[2*g]   + hres[t*128 + 2*g];
    float v1 = v2.y + bp[2*g+1] + hres[t*128 + 2*g + 1];
    float s = v0+v1, qq = v0*v0 + v1*v1;
    waveRed2(s,qq);
    float mean = s*(1.f/128), var = qq*(1.f/128) - mean*mean;
    float rs = rsqrtf(var + EPSV);
    float o0 = (v0-mean)*rs*gp[2*g]   + bgp[2*g];
    float o1 = (v1-mean)*rs*gp[2*g+1] + bgp[2*g+1];
    unsigned pk = (unsigned)f2b(o0) | ((unsigned)f2b(o1) << 16);
    *(unsigned*)&h1b[t*128 + 2*g] = pk;
    *(float2*)&h1f[t*128 + 2*g] = make_float2(o0, o1);
  }
  __syncthreads();

  // ---- stage B: [16 x 512] = h1[16 x 128] @ W1 (weights in regs) ----
  {
    const ushort_t* ap = h1b + m*128 + q*8;
    bf16x8 af[4];
    #pragma unroll
    for (int ks=0; ks<4; ++ks) af[ks] = *(const bf16x8*)(ap + ks*32);
    #pragma unroll
    for (int i=0;i<4;++i){
      int n0 = i*128 + wv*16;
      f32x4 acc = {0.f,0.f,0.f,0.f};
      #pragma unroll
      for (int ks=0; ks<4; ++ks)
        acc = __builtin_amdgcn_mfma_f32_16x16x32_bf16(af[ks], wfB[i*4+ks], acc, 0,0,0);
      float bb = b1[n0+m];
      #pragma unroll
      for (int r=0;r<4;++r)
        ub[(q*4+r)*512 + n0 + m] = f2b(fmaxf(acc[r] + bb, 0.f));
    }
  }
  __syncthreads();

  // ---- stage C: [16 x 128] = u[16 x 512] @ W2 (weights in regs) ----
  {
    f32x4 acc = {0.f,0.f,0.f,0.f};
    const ushort_t* ap = ub + m*512 + q*8;
    #pragma unroll
    for (int ks=0; ks<16; ++ks){
      bf16x8 af = *(const bf16x8*)(ap + ks*32);
      acc = __builtin_amdgcn_mfma_f32_16x16x32_bf16(af, wfC[ks], acc, 0,0,0);
    }
    #pragma unroll
    for (int r=0;r<4;++r) sA[(q*4+r)*128 + n0a + m] = acc[r];
  }
  __syncthreads();

  // ---- LN-C: residual h1f, write h (global) + hfin (pool) ----
  {
    int t = wv, g = lane;
    float2 v2 = *(const float2*)&sA[t*128 + 2*g];
    float v0 = v2.x + b2[2*g]   + h1f[t*128 + 2*g];
    float v1 = v2.y + b2[2*g+1] + h1f[t*128 + 2*g + 1];
    float s = v0+v1, qq = v0*v0 + v1*v1;
    waveRed2(s,qq);
    float mean = s*(1.f/128), var = qq*(1.f/128) - mean*mean;
    float rs = rsqrtf(var + EPSV);
    float o0 = (v0-mean)*rs*gf[2*g]   + bgf[2*g];
    float o1 = (v1-mean)*rs*gf[2*g+1] + bgf[2*g+1];
    *(float2*)&h[(size_t)(t0+t)*DD + 2*g] = make_float2(o0, o1);
    *(float2*)&hres[t*128 + 2*g] = make_float2(o0, o1);   // hfin
  }
  if (write_pool){
    __syncthreads();
    if (tid < 128){
      int n0 = t0 & 255;
      float m1 = hres[tid], m2 = -3.4e38f; int am = n0;
      #pragma unroll
      for (int p=1;p<TPB;++p)
        poolMerge(m1,m2,am, hres[p*128 + tid], -3.4e38f, n0+p);
      int blk = (t0 >> 3) & (BPL-1);
      size_t idx = ((size_t)b*BPL + blk)*DD + tid;
      qm1p[idx]=m1; qm2p[idx]=m2; qargp[idx]=am;
    }
  }
}

extern "C" void kernel_launch(void* const* d_in, const int* in_sizes, int n_in,
                              void* d_out, int out_size, void* d_ws, size_t ws_size,
                              hipStream_t stream)
{
  const float* x   = (const float*)d_in[0];
  const float* We  = (const float*)d_in[1];
  const float* be  = (const float*)d_in[2];
  const float* ge  = (const float*)d_in[3];
  const float* bge = (const float*)d_in[4];
  const float* Wp  = (const float*)d_in[5];
  const float* bp  = (const float*)d_in[6];
  const float* gp  = (const float*)d_in[7];
  const float* bgp = (const float*)d_in[8];
  const float* W1  = (const float*)d_in[9];
  const float* b1  = (const float*)d_in[10];
  const float* W2  = (const float*)d_in[11];
  const float* b2  = (const float*)d_in[12];
  const float* gf  = (const float*)d_in[13];
  const float* bgf = (const float*)d_in[14];

  // h lives in d_out; final layer's in-place update IS the output.
  float* h = (float*)d_out;
  char* ws = (char*)d_ws;
  const size_t NA = (size_t)BB*BPE*DD;       // 65536
  const size_t NB = (size_t)BB*BPL*DD;       // 32768
  float* pA1 = (float*)ws;                    ws += NA*4;
  float* pA2 = (float*)ws;                    ws += NA*4;
  int*   pAa = (int*)ws;                      ws += NA*4;
  float* pB1 = (float*)ws;                    ws += NB*4;
  float* pB2 = (float*)ws;                    ws += NB*4;
  int*   pBa = (int*)ws;                      ws += NB*4;
  ushort_t* wpT = (ushort_t*)ws;              ws += (size_t)LL*DD*2*DD*2;
  ushort_t* w1T = (ushort_t*)ws;              ws += (size_t)LL*HH*DD*2;
  ushort_t* w2T = (ushort_t*)ws;              ws += (size_t)LL*DD*HH*2;

  k_prep<<<NEMB + 320, 512, 0, stream>>>(x, We, be, ge, bge, h,
      pA1, pA2, pAa, Wp, W1, W2, wpT, w1T, w2T);

  k_layer<<<(BB*NN)/TPB, 512, 0, stream>>>(h, pA1, pA2, pAa, BPE,
      pB1, pB2, pBa, 1,
      wpT,                     bp,       gp,       bgp,
      w1T,                     b1,       w2T,      b2,
      gf,                      bgf);

  k_layer<<<(BB*NN)/TPB, 512, 0, stream>>>(h, pB1, pB2, pBa, BPL,
      pB1, pB2, pBa, 0,
      wpT + (size_t)DD*2*DD,   bp + DD,  gp + DD,  bgp + DD,
      w1T + (size_t)HH*DD,     b1 + HH,  w2T + (size_t)DD*HH, b2 + DD,
      gf + DD,                 bgf + DD);
}